// Round 1
// baseline (399.845 us; speedup 1.0000x reference)
//
#include <hip/hip_runtime.h>
#include <math.h>

// ---- problem constants ----
constexpr int kH    = 1024;  // GRU hidden
constexpr int kZ    = 1024;  // latent z
constexpr int kA    = 4;     // action dim
constexpr int kF    = 30;    // experts / horizon
constexpr int kDIN  = 2048;  // expert in (Z+H)
constexpr int kDH   = 512;   // expert hidden
constexpr int kEIN  = 1118;  // eval in (H + 94)
constexpr int kEH   = 512;   // eval hidden
constexpr int kEOUT = 94;    // eval out

// workspace layout (floats)
constexpr size_t GI_OFF   = 0;                          // 30*3072
constexpr size_t AGRU_OFF = GI_OFF + (size_t)kF*3*kH;   // 30*1024
constexpr size_t HACC_OFF = AGRU_OFF + (size_t)kF*kH;   // 30*2*512
constexpr size_t EHA_OFF  = HACC_OFF + (size_t)kF*2*kDH;// 512

__device__ __forceinline__ float sigmoidf_(float x) { return 1.0f / (1.0f + __expf(-x)); }

__device__ __forceinline__ float wave_reduce(float v) {
#pragma unroll
  for (int off = 32; off > 0; off >>= 1) v += __shfl_down(v, off, 64);
  return v;
}

// gi[t][r] = Wih[r,:] @ a_t[t,:] + bih[r]
__global__ __launch_bounds__(256) void gi_kernel(const float* __restrict__ Wih,
                                                 const float* __restrict__ bih,
                                                 const float* __restrict__ a_t,
                                                 float* __restrict__ gi,
                                                 const int* __restrict__ fptr) {
  int idx = blockIdx.x * 256 + threadIdx.x;  // t*3H + r
  if (idx >= kF * 3 * kH) return;
  int t = idx / (3 * kH);
  int r = idx - t * (3 * kH);
  if (t >= *fptr) return;
  float acc = bih[r];
#pragma unroll
  for (int k = 0; k < kA; k++) acc += Wih[r * kA + k] * a_t[t * kA + k];
  gi[idx] = acc;
}

// one GRU step: wave per hidden element j; rows j, j+H, j+2H of Whh
__global__ __launch_bounds__(256) void gru_step(const float* __restrict__ Whh,
                                                const float* __restrict__ bhh,
                                                const float* __restrict__ gi,
                                                const float* __restrict__ b_t,
                                                float* __restrict__ agru,
                                                int t,
                                                const int* __restrict__ fptr) {
  if (t >= *fptr) return;
  const float* hprev = (t == 0) ? b_t : (agru + (size_t)(t - 1) * kH);
  int wave = threadIdx.x >> 6;
  int lane = threadIdx.x & 63;
  int j = blockIdx.x * 4 + wave;  // 0..1023

  const float4* wr = (const float4*)(Whh + (size_t)j * kH);
  const float4* wz = (const float4*)(Whh + (size_t)(j + kH) * kH);
  const float4* wn = (const float4*)(Whh + (size_t)(j + 2 * kH) * kH);
  const float4* hv = (const float4*)hprev;

  float accr = 0.f, accz = 0.f, accn = 0.f;
#pragma unroll
  for (int k = lane; k < kH / 4; k += 64) {
    float4 hh = hv[k];
    float4 a = wr[k]; accr += a.x * hh.x + a.y * hh.y + a.z * hh.z + a.w * hh.w;
    float4 b = wz[k]; accz += b.x * hh.x + b.y * hh.y + b.z * hh.z + b.w * hh.w;
    float4 c = wn[k]; accn += c.x * hh.x + c.y * hh.y + c.z * hh.z + c.w * hh.w;
  }
  accr = wave_reduce(accr);
  accz = wave_reduce(accz);
  accn = wave_reduce(accn);

  if (lane == 0) {
    const float* git = gi + (size_t)t * 3 * kH;
    float gr = git[j] + accr + bhh[j];
    float gz = git[kH + j] + accz + bhh[kH + j];
    float hn = accn + bhh[2 * kH + j];
    float inn = git[2 * kH + j];
    float r = sigmoidf_(gr);
    float z = sigmoidf_(gz);
    float n = tanhf(inn + r * hn);
    agru[(size_t)t * kH + j] = (1.0f - z) * n + z * hprev[j];
  }
}

// stage1: expert first layers (split-K over 8 blocks/expert, pos+neg fused)
// plus eval first layer (8 blocks). atomicAdd partials into ws.
constexpr int EXP_SPLIT = 8;   // blocks per expert, 256 rows each
constexpr int EVAL_SPLIT = 8;  // blocks for eval, 140 rows each

__global__ __launch_bounds__(512) void stage1(const float* __restrict__ zpos,
                                              const float* __restrict__ zneg,
                                              const float* __restrict__ agru,
                                              const float* __restrict__ W1,
                                              const float* __restrict__ b_t,
                                              const float* __restrict__ ipo,
                                              const float* __restrict__ eW1,
                                              float* __restrict__ hacc,
                                              float* __restrict__ ehacc,
                                              const int* __restrict__ fptr) {
  int b = blockIdx.x;
  int tid = threadIdx.x;
  __shared__ float xs_p[256];
  __shared__ float xs_n[256];

  if (b < kF * EXP_SPLIT) {
    int i = b >> 3;
    int part = b & 7;
    if (i >= *fptr) return;
    int r0 = part * 256;
    if (tid < 256) {
      int r = r0 + tid;
      float xp, xn;
      if (r < kZ) { xp = zpos[(size_t)i * kZ + r]; xn = zneg[(size_t)i * kZ + r]; }
      else        { float v = agru[(size_t)i * kH + (r - kZ)]; xp = v; xn = v; }
      xs_p[tid] = xp;
      xs_n[tid] = xn;
    }
    __syncthreads();
    float ap = 0.f, an = 0.f;
    const float* w = W1 + ((size_t)i * kDIN + r0) * kDH + tid;
#pragma unroll 4
    for (int r = 0; r < 256; r++) {
      float wv = w[(size_t)r * kDH];
      ap += xs_p[r] * wv;
      an += xs_n[r] * wv;
    }
    atomicAdd(&hacc[((size_t)i * 2 + 0) * kDH + tid], ap);
    atomicAdd(&hacc[((size_t)i * 2 + 1) * kDH + tid], an);
  } else {
    // eval first layer
    int part = b - kF * EXP_SPLIT;  // 0..7
    int r0 = part * 140;
    int nrows = min(140, kEIN - r0);
    if (tid < nrows) {
      int r = r0 + tid;
      xs_p[tid < 256 ? tid : 0] = 0.f;  // unused; keep shared defined
    }
    __shared__ float xs[140];
    if (tid < nrows) {
      int r = r0 + tid;
      xs[tid] = (r < kH) ? b_t[r] : ipo[r - kH];
    }
    __syncthreads();
    float acc = 0.f;
    const float* w = eW1 + (size_t)r0 * kEH + tid;
    for (int r = 0; r < nrows; r++) acc += xs[r] * w[(size_t)r * kEH];
    atomicAdd(&ehacc[tid], acc);
  }
}

// stage2: second layers + biases + activations -> 154 outputs
__global__ __launch_bounds__(512) void stage2(const float* __restrict__ hacc,
                                              const float* __restrict__ ehacc,
                                              const float* __restrict__ b1,
                                              const float* __restrict__ W2,
                                              const float* __restrict__ b2,
                                              const float* __restrict__ eb1,
                                              const float* __restrict__ eW2,
                                              const float* __restrict__ eb2,
                                              float* __restrict__ out,
                                              const int* __restrict__ fptr) {
  int b = blockIdx.x;
  int tid = threadIdx.x;
  int f = *fptr;
  if (b < kF) {
    int i = b;
    if (i >= f) return;
    float bias = b1[(size_t)i * kDH + tid];
    float hp = fmaxf(hacc[((size_t)i * 2 + 0) * kDH + tid] + bias, 0.f);
    float hn = fmaxf(hacc[((size_t)i * 2 + 1) * kDH + tid] + bias, 0.f);
    float w = W2[(size_t)i * kDH + tid];
    float pp = hp * w, pn = hn * w;
    pp = wave_reduce(pp);
    pn = wave_reduce(pn);
    __shared__ float redp[8];
    __shared__ float redn[8];
    int wave = tid >> 6, lane = tid & 63;
    if (lane == 0) { redp[wave] = pp; redn[wave] = pn; }
    __syncthreads();
    if (tid == 0) {
      float sp = 0.f, sn = 0.f;
#pragma unroll
      for (int k = 0; k < 8; k++) { sp += redp[k]; sn += redn[k]; }
      out[i] = sp + b2[i];
      out[f + i] = sn + b2[i];
    }
  } else {
    // eval second layer: 94 outputs
    if (tid < kEOUT) {
      float acc = eb2[tid];
      for (int h = 0; h < kEH; h++) {
        float eh = fmaxf(ehacc[h] + eb1[h], 0.f);
        acc += eh * eW2[(size_t)h * kEOUT + tid];
      }
      out[2 * f + tid] = sigmoidf_(acc);
    }
  }
}

extern "C" void kernel_launch(void* const* d_in, const int* in_sizes, int n_in,
                              void* d_out, int out_size, void* d_ws, size_t ws_size,
                              hipStream_t stream) {
  const float* b_t    = (const float*)d_in[0];
  const float* a_t    = (const float*)d_in[1];
  const float* zpos   = (const float*)d_in[2];
  const float* zneg   = (const float*)d_in[3];
  const float* ipo    = (const float*)d_in[4];
  const float* gWih   = (const float*)d_in[5];
  const float* gWhh   = (const float*)d_in[6];
  const float* gbih   = (const float*)d_in[7];
  const float* gbhh   = (const float*)d_in[8];
  const float* mW1    = (const float*)d_in[9];
  const float* mb1    = (const float*)d_in[10];
  const float* mW2    = (const float*)d_in[11];
  const float* mb2    = (const float*)d_in[12];
  const float* eW1    = (const float*)d_in[13];
  const float* eb1    = (const float*)d_in[14];
  const float* eW2    = (const float*)d_in[15];
  const float* eb2    = (const float*)d_in[16];
  const int*   fptr   = (const int*)d_in[17];

  float* ws   = (float*)d_ws;
  float* gi   = ws + GI_OFF;
  float* agru = ws + AGRU_OFF;
  float* hacc = ws + HACC_OFF;
  float* ehacc= ws + EHA_OFF;
  float* out  = (float*)d_out;

  // zero the accumulators (hacc + ehacc are contiguous)
  hipMemsetAsync(hacc, 0, (size_t)(kF * 2 * kDH + kEH) * sizeof(float), stream);

  // gi precompute
  gi_kernel<<<(kF * 3 * kH + 255) / 256, 256, 0, stream>>>(gWih, gbih, a_t, gi, fptr);

  // 30 sequential GRU steps
  for (int t = 0; t < kF; t++) {
    gru_step<<<kH / 4, 256, 0, stream>>>(gWhh, gbhh, gi, b_t, agru, t, fptr);
  }

  // expert + eval first layers
  stage1<<<kF * EXP_SPLIT + EVAL_SPLIT, 512, 0, stream>>>(zpos, zneg, agru, mW1, b_t,
                                                          ipo, eW1, hacc, ehacc, fptr);

  // second layers -> outputs
  stage2<<<kF + 1, 512, 0, stream>>>(hacc, ehacc, mb1, mW2, mb2, eb1, eW2, eb2, out, fptr);
}